// Round 6
// baseline (258.593 us; speedup 1.0000x reference)
//
#include <hip/hip_runtime.h>

// QRNN fused: causal conv1d(window=2) as f16 MFMA GEMM + gates + fo-pool scan.
// Shapes: B=8, T=2048, C=1024, U=1024 -> GEMM M=16384, K=2048, N=3072.
// R6: (1) MFMA reorder: ks-outer so 8 independent MFMAs between acc reuses
//     (R5 chained acc=mfma(ks0);acc=mfma(ks1) -> latency-bound matrix pipe).
//     (2) deeper staging: all 4 next-tile halves issued at P1/P2; vmcnt waits
//     now cover >=2-3 phases (HBM latency fully hidden).

typedef _Float16 f16;
typedef _Float16 f16x8 __attribute__((ext_vector_type(8)));
typedef float    f32x4 __attribute__((ext_vector_type(4)));

#define Bq 8
#define Tq 2048
#define Cq 1024
#define Uq 1024
#define Mq (Bq*Tq)    // 16384
#define Kq (2*Cq)     // 2048
#define Nq (3*Uq)     // 3072
#define NCH 32
#define CHL (Tq/NCH)

#define AS1 __attribute__((address_space(1)))
#define AS3 __attribute__((address_space(3)))

// ---------------- prep: Xs[b][1+t][c] = x[b][t][c] (f16), Xs[b][0][:] = 0 ----------------
__global__ void prep_xs(const float* __restrict__ x, f16* __restrict__ Xs) {
    long long idx = ((long long)blockIdx.x * blockDim.x + threadIdx.x) * 8;
    int c = (int)(idx & (Cq - 1));
    long long row = idx >> 10;
    int tp = (int)(row % (Tq + 1));
    int b  = (int)(row / (Tq + 1));
    f16x8 o;
    if (tp == 0) {
#pragma unroll
        for (int j = 0; j < 8; j++) o[j] = (f16)0.0f;
    } else {
        const float* src = x + (((size_t)b * Tq + (tp - 1)) << 10) + c;
        float4 v0 = *(const float4*)(src);
        float4 v1 = *(const float4*)(src + 4);
        o[0]=(f16)v0.x; o[1]=(f16)v0.y; o[2]=(f16)v0.z; o[3]=(f16)v0.w;
        o[4]=(f16)v1.x; o[5]=(f16)v1.y; o[6]=(f16)v1.z; o[7]=(f16)v1.w;
    }
    *(f16x8*)(Xs + idx) = o;
}

// ---------------- prep: W^T f16 [N=3072][K=2048] ----------------
__global__ void prep_wt(const float* __restrict__ w, f16* __restrict__ WT) {
    __shared__ float t[32][33];
    int kb = blockIdx.x * 32, nb = blockIdx.y * 32;
    int tx = threadIdx.x & 31, ty = threadIdx.x >> 5;
#pragma unroll
    for (int j = 0; j < 32; j += 8)
        t[ty + j][tx] = w[(size_t)(kb + ty + j) * Nq + nb + tx];
    __syncthreads();
#pragma unroll
    for (int j = 0; j < 32; j += 8)
        WT[(size_t)(nb + ty + j) * Kq + kb + tx] = (f16)t[tx][ty + j];
}

// ---------------- 256x256 pipelined 4-phase GEMM + gate epilogue ----------------
// 8 waves (2M x 4N). Phase (h,g) = 16 MFMA 16x16x32 (ks-outer independent order).
// LDS [A0|B0|A1|B1] 32KB each, dbuf 128KiB, swizzle lds(row,cb)=global(row,cb^((row&7)<<4)).
// Register pipeline: ds_reads lead their consuming phase by one (counted lgkmcnt).
// Staging pipeline: tile+1's 4 halves all issued at P1(A0',B0')/P2(B1',A1');
// vmcnt(4)@end-P1 drains prev-tile A1' (read at P2), vmcnt(4)@end-P3 drains
// A0',B0' (read at P4), vmcnt(2)@end-P4 drains B1' (read next-P1).
__global__ __launch_bounds__(512, 2) void gemm_gates8(
    const f16* __restrict__ Xs, const f16* __restrict__ WT,
    const float* __restrict__ bias,
    f16* __restrict__ H, f16* __restrict__ F, f16* __restrict__ O)
{
    __shared__ __align__(16) f16 smem[65536];   // 128 KiB
    const int tid  = threadIdx.x;
    const int lane = tid & 63;
    const int wave = tid >> 6;
    const int wm = wave >> 2;            // 0..1
    const int wn = wave & 3;             // 0..3

    // T1: XCD swizzle, nwg=768 (768%8==0), chunk=96, N-minor for A-panel L2 reuse
    const int wg  = blockIdx.x;
    const int swz = (wg & 7) * 96 + (wg >> 3);
    const int mT  = swz / 12, nT = swz - mT * 12;
    const int rM  = mT * 256;
    const int nB  = nT * 256;
    const int b   = rM >> 11;
    const int t0  = rM & (Tq - 1);
    const size_t xsRow0 = (size_t)b * (Tq + 1) + t0;

    const int srow = tid >> 3;
    const int scol = (((tid & 7) ^ (srow & 7))) * 8;   // pre-swizzled source col (f16)
    const f16* Abase = Xs + (xsRow0 + srow) * (size_t)Cq + scol;   // lda = Cq (overlapping windows)
    const f16* Bbase = WT + (size_t)(nB + srow) * Kq + scol;
    const int dstT = tid * 16;

#define STAGE_A(c, h, kt) do { \
    const f16* _s = Abase + (size_t)((h) * 128) * Cq + (kt) * 64; \
    int _d = (c) * 65536 + (h) * 16384 + dstT; \
    __builtin_amdgcn_global_load_lds((const AS1 void*)_s, \
        (AS3 void*)((char*)smem + _d), 16, 0, 0); \
    __builtin_amdgcn_global_load_lds((const AS1 void*)(_s + (size_t)64 * Cq), \
        (AS3 void*)((char*)smem + _d + 8192), 16, 0, 0); \
} while (0)

#define STAGE_B(c, h, kt) do { \
    const f16* _s = Bbase + (size_t)((h) * 128) * Kq + (kt) * 64; \
    int _d = 32768 + (c) * 65536 + (h) * 16384 + dstT; \
    __builtin_amdgcn_global_load_lds((const AS1 void*)_s, \
        (AS3 void*)((char*)smem + _d), 16, 0, 0); \
    __builtin_amdgcn_global_load_lds((const AS1 void*)(_s + (size_t)64 * Kq), \
        (AS3 void*)((char*)smem + _d + 8192), 16, 0, 0); \
} while (0)

    // ds_read per-lane constants (16x16x32 fragment layout)
    const int rAoff = (wm * 64 + (lane & 15)) * 128;
    const int rBoff = (wn * 32 + (lane & 15)) * 128;
    const int ksw0 = (((lane >> 4) * 16)) ^ ((lane & 7) << 4);
    const int ksw1 = (64 + ((lane >> 4) * 16)) ^ ((lane & 7) << 4);

    f32x4 acc[2][2][4][2] = {};   // [h][g][mi][ni]
    f16x8 afA[4][2], afB[4][2], bg0[2][2], bg1[2][2];

#define LOADA_TO(c, h, dst) do { \
    const char* _a = (const char*)smem + (c) * 65536 + (h) * 16384 + rAoff; \
    _Pragma("unroll") \
    for (int mi = 0; mi < 4; mi++) { \
        dst[mi][0] = *(const f16x8*)(_a + mi * 2048 + ksw0); \
        dst[mi][1] = *(const f16x8*)(_a + mi * 2048 + ksw1); \
    } \
} while (0)

#define LOADB_TO(c, g, breg) do { \
    const char* _b = (const char*)smem + 32768 + (c) * 65536 + (g) * 16384 + rBoff; \
    _Pragma("unroll") \
    for (int ni = 0; ni < 2; ni++) { \
        breg[ni][0] = *(const f16x8*)(_b + ni * 2048 + ksw0); \
        breg[ni][1] = *(const f16x8*)(_b + ni * 2048 + ksw1); \
    } \
} while (0)

// ks-outer: 8 independent MFMAs per ks; acc reuse distance = 8 issues.
#define MM(h, g, afr, breg) do { \
    _Pragma("unroll") \
    for (int ks = 0; ks < 2; ks++) \
    _Pragma("unroll") \
    for (int mi = 0; mi < 4; mi++) \
    _Pragma("unroll") \
    for (int ni = 0; ni < 2; ni++) \
        acc[h][g][mi][ni] = __builtin_amdgcn_mfma_f32_16x16x32_f16(afr[mi][ks], breg[ni][ks], acc[h][g][mi][ni], 0, 0, 0); \
} while (0)

#define BAR()  __builtin_amdgcn_s_barrier()
#define SB0()  __builtin_amdgcn_sched_barrier(0)
#define PRIO1  __builtin_amdgcn_s_setprio(1)
#define PRIO0  __builtin_amdgcn_s_setprio(0)
#define LGKMC(n) asm volatile("s_waitcnt lgkmcnt(" #n ")" ::: "memory")
#define VMC(n)   asm volatile("s_waitcnt vmcnt(" #n ")" ::: "memory")

// K-tile on buf c; stages tile ktn's 4 halves into buf c^1 at P1/P2.
// lgkm counts = reads issued THIS phase (drains exactly the previous phase's).
// vmcnt chain (per-thread instr units, 2 per half; verified in-order):
//   end-P1 vmcnt(4): outstanding = prevA1'(2)+P1(4)=6 -> drains prev A1' (read P2)
//   end-P3 vmcnt(4): outstanding = A1'... P1(4)+P2(4)=8 -> drains A0',B0' (read P4)
//   end-P4 vmcnt(2): outstanding = B1',A1'(4) -> drains B1' (read next-P1)
#define KTILE(c, ktn) do { \
    /*P1*/ LOADB_TO(c, 1, bg1); STAGE_A(1 - (c), 0, ktn); STAGE_B(1 - (c), 0, ktn); \
           SB0(); LGKMC(4); SB0(); \
           PRIO1; MM(0, 0, afA, bg0); PRIO0; \
           VMC(4); BAR(); \
    /*P2*/ LOADA_TO(c, 1, afB); STAGE_B(1 - (c), 1, ktn); STAGE_A(1 - (c), 1, ktn); \
           SB0(); LGKMC(8); SB0(); \
           PRIO1; MM(0, 1, afA, bg1); PRIO0; \
    /*P3*/ SB0(); LGKMC(0); SB0(); \
           PRIO1; MM(1, 0, afB, bg0); PRIO0; \
           VMC(4); BAR(); \
    /*P4*/ LOADA_TO(1 - (c), 0, afA); LOADB_TO(1 - (c), 0, bg0); \
           SB0(); LGKMC(12); SB0(); \
           PRIO1; MM(1, 1, afB, bg1); PRIO0; \
           VMC(2); BAR(); \
} while (0)

    // prologue: stage all 4 halves of K-tile 0 into buf0; drain all (once),
    // barrier, then pre-read A0,B0 fragments (drained by P1's LGKMC(4)).
    STAGE_A(0, 0, 0); STAGE_B(0, 0, 0); STAGE_B(0, 1, 0); STAGE_A(0, 1, 0);
    VMC(0);
    BAR();
    LOADA_TO(0, 0, afA); LOADB_TO(0, 0, bg0);

    for (int t = 0; t < 32; t += 2) {
        KTILE(0, t + 1);
        KTILE(1, t + 2);   // t+2==32 on last iter: garbage stage/pre-read, in-bounds, never consumed
    }

    // epilogue: C/D layout col=lane&15, row=(lane>>4)*4+j
    const int gate = nB >> 10;
    f16* G = (gate == 0) ? H : ((gate == 1) ? F : O);
#pragma unroll
    for (int h = 0; h < 2; h++)
#pragma unroll
    for (int g = 0; g < 2; g++)
#pragma unroll
    for (int ni = 0; ni < 2; ni++) {
        const int col = nB + g * 128 + wn * 32 + ni * 16 + (lane & 15);
        const int u = col & (Uq - 1);
        const float bv = bias[col];
#pragma unroll
        for (int mi = 0; mi < 4; mi++)
#pragma unroll
        for (int j = 0; j < 4; j++) {
            const int row = rM + h * 128 + wm * 64 + mi * 16 + ((lane >> 4) << 2) + j;
            float v = acc[h][g][mi][ni][j] + bv;
            float r;
            if (gate == 0) r = 1.0f - 2.0f / (__expf(2.0f * v) + 1.0f);  // tanh
            else           r = 1.0f / (1.0f + __expf(-v));                // sigmoid
            G[(size_t)row * Uq + u] = (f16)r;
        }
    }
}

// ---------------- fo-pool scan (chunked, 3 passes) ----------------
__global__ void scan_pass1(const f16* __restrict__ F, const f16* __restrict__ H,
                           float* __restrict__ Ach, float* __restrict__ Bch) {
    int idx = blockIdx.x * blockDim.x + threadIdx.x;
    int u  = idx & (Uq - 1);
    int ch = (idx >> 10) & (NCH - 1);
    int b  = idx >> 15;
    size_t base = ((size_t)b * Tq + ch * CHL) * Uq + u;
    float a = 1.0f, c = 0.0f;
    for (int i = 0; i < CHL; i++) {
        float f = (float)F[base + (size_t)i * Uq];
        float h = (float)H[base + (size_t)i * Uq];
        c = f * c + (1.0f - f) * h;
        a *= f;
    }
    Ach[idx] = a;
    Bch[idx] = c;
}

__global__ void scan_pass2(const float* __restrict__ Ach, const float* __restrict__ Bch,
                           float* __restrict__ Cin) {
    int idx = blockIdx.x * blockDim.x + threadIdx.x;
    int u = idx & (Uq - 1);
    int b = idx >> 10;
    float c = 0.0f;
    for (int ch = 0; ch < NCH; ch++) {
        int o = ((b * NCH) + ch) * Uq + u;
        Cin[o] = c;
        c = Ach[o] * c + Bch[o];
    }
}

__global__ void scan_pass3(const f16* __restrict__ F, const f16* __restrict__ H,
                           const f16* __restrict__ O, const float* __restrict__ Cin,
                           float* __restrict__ out) {
    int idx = blockIdx.x * blockDim.x + threadIdx.x;
    int u  = idx & (Uq - 1);
    int ch = (idx >> 10) & (NCH - 1);
    int b  = idx >> 15;
    size_t base = ((size_t)b * Tq + ch * CHL) * Uq + u;
    float c = Cin[idx];
    for (int i = 0; i < CHL; i++) {
        float f = (float)F[base + (size_t)i * Uq];
        float h = (float)H[base + (size_t)i * Uq];
        c = f * c + (1.0f - f) * h;
        out[base + (size_t)i * Uq] = (float)O[base + (size_t)i * Uq] * c;
    }
}

// ---------------- launch ----------------
extern "C" void kernel_launch(void* const* d_in, const int* in_sizes, int n_in,
                              void* d_out, int out_size, void* d_ws, size_t ws_size,
                              hipStream_t stream) {
    const float* x    = (const float*)d_in[0];
    const float* w    = (const float*)d_in[1];
    const float* bias = (const float*)d_in[2];
    float* out = (float*)d_out;
    char* ws = (char*)d_ws;

    f16* Xs   = (f16*)(ws);                       // 8*2049*1024*2 = 33,570,816
    f16* WT   = (f16*)(ws + 33570816);            // 12,582,912
    f16* Hh   = (f16*)(ws + 46153728);            // 33,554,432
    f16* Fh   = (f16*)(ws + 79708160);            // 33,554,432
    f16* Oh   = (f16*)(ws + 113262592);           // 33,554,432
    float* Ach = (float*)(ws + 146817024);        // 1,048,576
    float* Bch = (float*)(ws + 147865600);        // 1,048,576
    float* Cin = (float*)(ws + 148914176);        // 1,048,576

    prep_xs<<<(Bq * (Tq + 1) * Cq) / (8 * 256), 256, 0, stream>>>(x, Xs);
    prep_wt<<<dim3(Kq / 32, Nq / 32), 256, 0, stream>>>(w, WT);
    gemm_gates8<<<(Mq / 256) * (Nq / 256), 512, 0, stream>>>(Xs, WT, bias, Hh, Fh, Oh);
    scan_pass1<<<(Bq * NCH * Uq) / 256, 256, 0, stream>>>(Fh, Hh, Ach, Bch);
    scan_pass2<<<(Bq * Uq) / 256, 256, 0, stream>>>(Ach, Bch, Cin);
    scan_pass3<<<(Bq * NCH * Uq) / 256, 256, 0, stream>>>(Fh, Hh, Oh, Cin, out);
}

// Round 7
// 254.885 us; speedup vs baseline: 1.0146x; 1.0146x over previous
//
#include <hip/hip_runtime.h>

// QRNN fused: causal conv1d(window=2) as f16 MFMA GEMM + gates + fo-pool scan.
// Shapes: B=8, T=2048, C=1024, U=1024 -> GEMM M=16384, K=2048, N=3072.
// R7: balanced LDS-read schedule (6 ds_read_b128/wave/phase, was 4/8/0/12) so
//     reads fit under the 620-cyc MFMA window; 2 sync points per K-tile
//     (end-P2, end-P4). scan_pass2 folded into pass3 (inline carry scan).

typedef _Float16 f16;
typedef _Float16 f16x8 __attribute__((ext_vector_type(8)));
typedef float    f32x4 __attribute__((ext_vector_type(4)));

#define Bq 8
#define Tq 2048
#define Cq 1024
#define Uq 1024
#define Mq (Bq*Tq)    // 16384
#define Kq (2*Cq)     // 2048
#define Nq (3*Uq)     // 3072
#define NCH 32
#define CHL (Tq/NCH)

#define AS1 __attribute__((address_space(1)))
#define AS3 __attribute__((address_space(3)))

// ---------------- prep: Xs[b][1+t][c] = x[b][t][c] (f16), Xs[b][0][:] = 0 ----------------
__global__ void prep_xs(const float* __restrict__ x, f16* __restrict__ Xs) {
    long long idx = ((long long)blockIdx.x * blockDim.x + threadIdx.x) * 8;
    int c = (int)(idx & (Cq - 1));
    long long row = idx >> 10;
    int tp = (int)(row % (Tq + 1));
    int b  = (int)(row / (Tq + 1));
    f16x8 o;
    if (tp == 0) {
#pragma unroll
        for (int j = 0; j < 8; j++) o[j] = (f16)0.0f;
    } else {
        const float* src = x + (((size_t)b * Tq + (tp - 1)) << 10) + c;
        float4 v0 = *(const float4*)(src);
        float4 v1 = *(const float4*)(src + 4);
        o[0]=(f16)v0.x; o[1]=(f16)v0.y; o[2]=(f16)v0.z; o[3]=(f16)v0.w;
        o[4]=(f16)v1.x; o[5]=(f16)v1.y; o[6]=(f16)v1.z; o[7]=(f16)v1.w;
    }
    *(f16x8*)(Xs + idx) = o;
}

// ---------------- prep: W^T f16 [N=3072][K=2048] ----------------
__global__ void prep_wt(const float* __restrict__ w, f16* __restrict__ WT) {
    __shared__ float t[32][33];
    int kb = blockIdx.x * 32, nb = blockIdx.y * 32;
    int tx = threadIdx.x & 31, ty = threadIdx.x >> 5;
#pragma unroll
    for (int j = 0; j < 32; j += 8)
        t[ty + j][tx] = w[(size_t)(kb + ty + j) * Nq + nb + tx];
    __syncthreads();
#pragma unroll
    for (int j = 0; j < 32; j += 8)
        WT[(size_t)(nb + ty + j) * Kq + kb + tx] = (f16)t[tx][ty + j];
}

// ---------------- 256x256 pipelined 4-phase GEMM + gate epilogue ----------------
// 8 waves (2M x 4N). Phase (h,g) = 16 MFMA 16x16x32.
// LDS [A0|B0|A1|B1] 32KB each, dbuf 128KiB, swizzle lds(row,cb)=global(row,cb^((row&7)<<4)).
// Reads balanced 6/wave/phase, lead >=1 phase before first consumption:
//   P1: bg1(4)+afB[0](2)  P2: afB[1:4](6)  P3: afA'[0:3](6)  P4: afA'[3](2)+bg0'(4)
// lgkm waits: P1 LGKMC(6) [drains prev P3+P4's 12], P2 LGKMC(8) [drains bg1],
//   P3 LGKMC(6) [drains afB], P4 none (operands already drained).
// Stages: P1 A0'+B0', P2 B1'+A1'. Sync: VMC(4)+BAR @end-P2 (drains A0'/B0',
//   read from P3), VMC(0)+BAR @end-P4 (drains B1'/A1', read from next-P1).
__global__ __launch_bounds__(512, 2) void gemm_gates8(
    const f16* __restrict__ Xs, const f16* __restrict__ WT,
    const float* __restrict__ bias,
    f16* __restrict__ H, f16* __restrict__ F, f16* __restrict__ O)
{
    __shared__ __align__(16) f16 smem[65536];   // 128 KiB
    const int tid  = threadIdx.x;
    const int lane = tid & 63;
    const int wave = tid >> 6;
    const int wm = wave >> 2;            // 0..1
    const int wn = wave & 3;             // 0..3

    // T1: XCD swizzle, nwg=768 (768%8==0), chunk=96, N-minor for A-panel L2 reuse
    const int wg  = blockIdx.x;
    const int swz = (wg & 7) * 96 + (wg >> 3);
    const int mT  = swz / 12, nT = swz - mT * 12;
    const int rM  = mT * 256;
    const int nB  = nT * 256;
    const int b   = rM >> 11;
    const int t0  = rM & (Tq - 1);
    const size_t xsRow0 = (size_t)b * (Tq + 1) + t0;

    const int srow = tid >> 3;
    const int scol = (((tid & 7) ^ (srow & 7))) * 8;   // pre-swizzled source col (f16)
    const f16* Abase = Xs + (xsRow0 + srow) * (size_t)Cq + scol;   // lda = Cq (overlapping windows)
    const f16* Bbase = WT + (size_t)(nB + srow) * Kq + scol;
    const int dstT = tid * 16;

#define STAGE_A(c, h, kt) do { \
    const f16* _s = Abase + (size_t)((h) * 128) * Cq + (kt) * 64; \
    int _d = (c) * 65536 + (h) * 16384 + dstT; \
    __builtin_amdgcn_global_load_lds((const AS1 void*)_s, \
        (AS3 void*)((char*)smem + _d), 16, 0, 0); \
    __builtin_amdgcn_global_load_lds((const AS1 void*)(_s + (size_t)64 * Cq), \
        (AS3 void*)((char*)smem + _d + 8192), 16, 0, 0); \
} while (0)

#define STAGE_B(c, h, kt) do { \
    const f16* _s = Bbase + (size_t)((h) * 128) * Kq + (kt) * 64; \
    int _d = 32768 + (c) * 65536 + (h) * 16384 + dstT; \
    __builtin_amdgcn_global_load_lds((const AS1 void*)_s, \
        (AS3 void*)((char*)smem + _d), 16, 0, 0); \
    __builtin_amdgcn_global_load_lds((const AS1 void*)(_s + (size_t)64 * Kq), \
        (AS3 void*)((char*)smem + _d + 8192), 16, 0, 0); \
} while (0)

    // ds_read per-lane constants (16x16x32 fragment layout)
    const int rAoff = (wm * 64 + (lane & 15)) * 128;
    const int rBoff = (wn * 32 + (lane & 15)) * 128;
    const int ksw0 = (((lane >> 4) * 16)) ^ ((lane & 7) << 4);
    const int ksw1 = (64 + ((lane >> 4) * 16)) ^ ((lane & 7) << 4);

    f32x4 acc[2][2][4][2] = {};   // [h][g][mi][ni]
    f16x8 afA[4][2], afB[4][2], bg0[2][2], bg1[2][2];

#define LOADA_PART(c, h, dst, mlo, mhi) do { \
    const char* _a = (const char*)smem + (c) * 65536 + (h) * 16384 + rAoff; \
    _Pragma("unroll") \
    for (int mi = (mlo); mi < (mhi); mi++) { \
        dst[mi][0] = *(const f16x8*)(_a + mi * 2048 + ksw0); \
        dst[mi][1] = *(const f16x8*)(_a + mi * 2048 + ksw1); \
    } \
} while (0)

#define LOADB_TO(c, g, breg) do { \
    const char* _b = (const char*)smem + 32768 + (c) * 65536 + (g) * 16384 + rBoff; \
    _Pragma("unroll") \
    for (int ni = 0; ni < 2; ni++) { \
        breg[ni][0] = *(const f16x8*)(_b + ni * 2048 + ksw0); \
        breg[ni][1] = *(const f16x8*)(_b + ni * 2048 + ksw1); \
    } \
} while (0)

// ks-outer: 8 independent MFMAs between accumulator reuses
#define MM(h, g, afr, breg) do { \
    _Pragma("unroll") \
    for (int ks = 0; ks < 2; ks++) \
    _Pragma("unroll") \
    for (int mi = 0; mi < 4; mi++) \
    _Pragma("unroll") \
    for (int ni = 0; ni < 2; ni++) \
        acc[h][g][mi][ni] = __builtin_amdgcn_mfma_f32_16x16x32_f16(afr[mi][ks], breg[ni][ks], acc[h][g][mi][ni], 0, 0, 0); \
} while (0)

#define BAR()  __builtin_amdgcn_s_barrier()
#define SB0()  __builtin_amdgcn_sched_barrier(0)
#define PRIO1  __builtin_amdgcn_s_setprio(1)
#define PRIO0  __builtin_amdgcn_s_setprio(0)
#define LGKMC(n) asm volatile("s_waitcnt lgkmcnt(" #n ")" ::: "memory")
#define VMC(n)   asm volatile("s_waitcnt vmcnt(" #n ")" ::: "memory")

#define KTILE(c, ktn) do { \
    /*P1*/ LOADB_TO(c, 1, bg1); LOADA_PART(c, 1, afB, 0, 1); \
           STAGE_A(1 - (c), 0, ktn); STAGE_B(1 - (c), 0, ktn); \
           SB0(); LGKMC(6); SB0(); \
           PRIO1; MM(0, 0, afA, bg0); PRIO0; \
    /*P2*/ LOADA_PART(c, 1, afB, 1, 4); \
           STAGE_B(1 - (c), 1, ktn); STAGE_A(1 - (c), 1, ktn); \
           SB0(); LGKMC(8); SB0(); \
           PRIO1; MM(0, 1, afA, bg1); PRIO0; \
           VMC(4); BAR(); \
    /*P3*/ LOADA_PART(1 - (c), 0, afA, 0, 3); \
           SB0(); LGKMC(6); SB0(); \
           PRIO1; MM(1, 0, afB, bg0); PRIO0; \
    /*P4*/ LOADA_PART(1 - (c), 0, afA, 3, 4); LOADB_TO(1 - (c), 0, bg0); \
           SB0(); \
           PRIO1; MM(1, 1, afB, bg1); PRIO0; \
           VMC(0); BAR(); \
} while (0)

    // prologue: stage all 4 halves of K-tile 0 into buf0; full drain + barrier;
    // pre-read afA(8)+bg0(4) (drained by first P1's LGKMC(6)).
    STAGE_A(0, 0, 0); STAGE_B(0, 0, 0); STAGE_B(0, 1, 0); STAGE_A(0, 1, 0);
    VMC(0);
    BAR();
    LOADA_PART(0, 0, afA, 0, 4); LOADB_TO(0, 0, bg0);

    for (int t = 0; t < 32; t += 2) {
        KTILE(0, t + 1);
        KTILE(1, t + 2);   // t+2==32 on last iter: garbage stage/pre-read, in-bounds, never consumed
    }

    // epilogue: C/D layout col=lane&15, row=(lane>>4)*4+j
    const int gate = nB >> 10;
    f16* G = (gate == 0) ? H : ((gate == 1) ? F : O);
#pragma unroll
    for (int h = 0; h < 2; h++)
#pragma unroll
    for (int g = 0; g < 2; g++)
#pragma unroll
    for (int ni = 0; ni < 2; ni++) {
        const int col = nB + g * 128 + wn * 32 + ni * 16 + (lane & 15);
        const int u = col & (Uq - 1);
        const float bv = bias[col];
#pragma unroll
        for (int mi = 0; mi < 4; mi++)
#pragma unroll
        for (int j = 0; j < 4; j++) {
            const int row = rM + h * 128 + wm * 64 + mi * 16 + ((lane >> 4) << 2) + j;
            float v = acc[h][g][mi][ni][j] + bv;
            float r;
            if (gate == 0) r = 1.0f - 2.0f / (__expf(2.0f * v) + 1.0f);  // tanh
            else           r = 1.0f / (1.0f + __expf(-v));                // sigmoid
            G[(size_t)row * Uq + u] = (f16)r;
        }
    }
}

// ---------------- fo-pool scan (chunked, 2 passes) ----------------
__global__ void scan_pass1(const f16* __restrict__ F, const f16* __restrict__ H,
                           float* __restrict__ Ach, float* __restrict__ Bch) {
    int idx = blockIdx.x * blockDim.x + threadIdx.x;
    int u  = idx & (Uq - 1);
    int ch = (idx >> 10) & (NCH - 1);
    int b  = idx >> 15;
    size_t base = ((size_t)b * Tq + ch * CHL) * Uq + u;
    float a = 1.0f, c = 0.0f;
    for (int i = 0; i < CHL; i++) {
        float f = (float)F[base + (size_t)i * Uq];
        float h = (float)H[base + (size_t)i * Uq];
        c = f * c + (1.0f - f) * h;
        a *= f;
    }
    Ach[idx] = a;
    Bch[idx] = c;
}

// pass3 with inlined carry scan (was pass2): carry = scan of chunk (a,b) pairs
// over ch' < ch. Ach/Bch are 2 MB (L2-resident); loop count uniform per block.
__global__ void scan_pass3(const f16* __restrict__ F, const f16* __restrict__ H,
                           const f16* __restrict__ O,
                           const float* __restrict__ Ach, const float* __restrict__ Bch,
                           float* __restrict__ out) {
    int idx = blockIdx.x * blockDim.x + threadIdx.x;
    int u  = idx & (Uq - 1);
    int ch = (idx >> 10) & (NCH - 1);
    int b  = idx >> 15;
    int cbase = (b * NCH) * Uq + u;
    float c = 0.0f;
    for (int ch2 = 0; ch2 < ch; ch2++) {
        int o = cbase + ch2 * Uq;
        c = Ach[o] * c + Bch[o];
    }
    size_t base = ((size_t)b * Tq + ch * CHL) * Uq + u;
    for (int i = 0; i < CHL; i++) {
        float f = (float)F[base + (size_t)i * Uq];
        float h = (float)H[base + (size_t)i * Uq];
        c = f * c + (1.0f - f) * h;
        out[base + (size_t)i * Uq] = (float)O[base + (size_t)i * Uq] * c;
    }
}

// ---------------- launch ----------------
extern "C" void kernel_launch(void* const* d_in, const int* in_sizes, int n_in,
                              void* d_out, int out_size, void* d_ws, size_t ws_size,
                              hipStream_t stream) {
    const float* x    = (const float*)d_in[0];
    const float* w    = (const float*)d_in[1];
    const float* bias = (const float*)d_in[2];
    float* out = (float*)d_out;
    char* ws = (char*)d_ws;

    f16* Xs   = (f16*)(ws);                       // 8*2049*1024*2 = 33,570,816
    f16* WT   = (f16*)(ws + 33570816);            // 12,582,912
    f16* Hh   = (f16*)(ws + 46153728);            // 33,554,432
    f16* Fh   = (f16*)(ws + 79708160);            // 33,554,432
    f16* Oh   = (f16*)(ws + 113262592);           // 33,554,432
    float* Ach = (float*)(ws + 146817024);        // 1,048,576
    float* Bch = (float*)(ws + 147865600);        // 1,048,576

    prep_xs<<<(Bq * (Tq + 1) * Cq) / (8 * 256), 256, 0, stream>>>(x, Xs);
    prep_wt<<<dim3(Kq / 32, Nq / 32), 256, 0, stream>>>(w, WT);
    gemm_gates8<<<(Mq / 256) * (Nq / 256), 512, 0, stream>>>(Xs, WT, bias, Hh, Fh, Oh);
    scan_pass1<<<(Bq * NCH * Uq) / 256, 256, 0, stream>>>(Fh, Hh, Ach, Bch);
    scan_pass3<<<(Bq * NCH * Uq) / 256, 256, 0, stream>>>(Fh, Hh, Oh, Ach, Bch, out);
}